// Round 5
// baseline (280.393 us; speedup 1.0000x reference)
//
#include <hip/hip_runtime.h>

// NetVladCNN: B=64, D=512, H=W=32 (N=1024), K=64
// K1 : FUSED conv+softmax per (b, 4-w-column) block: tile 64k x 128j (j=h*4+wl,
//      all 32 h in-block). x staged f32 via global_load_lds double-buffer with
//      additive slot swizzle (2 lanes/bank frag reads = floor); w A-frags direct
//      global f32, register-prefetched. Softmax over h in LDS -> a bf16 (B,K,N).
// K2 : V = a @ x^T - 32*c per (b, 64d). x via glds, granule swizzle
//      col=4*(s^(r&7)) -> b128 frag reads at the 8-access/bank floor; a frags
//      direct global bf16 prefetched. Fused L2-normalize over k -> yw (B,K,D).
// K3 : transpose -> out (D,K,B)
// XCD: blk%8 = b%8 -> all same-b blocks on one XCD; 512 blocks fully resident.

typedef __attribute__((ext_vector_type(8))) short short8;
typedef __attribute__((ext_vector_type(4))) float f32x4;
typedef unsigned short u16;
typedef unsigned int u32;

union S8u { u32 q[4]; short8 s; };

__device__ __forceinline__ u32 pk2(float lo, float hi) {  // RNE bf16 pair pack
  union { float f; u32 u; } a, b; a.f = lo; b.f = hi;
  u32 xl = (a.u + 0x7fffu + ((a.u >> 16) & 1u)) >> 16;
  u32 xh = (b.u + 0x7fffu + ((b.u >> 16) & 1u)) & 0xffff0000u;
  return xl | xh;
}

__device__ __forceinline__ u16 bf1(float f) {
  union { float f; u32 u; } a; a.f = f;
  return (u16)((a.u + 0x7fffu + ((a.u >> 16) & 1u)) >> 16);
}

typedef const __attribute__((address_space(1))) u32 GU32;
typedef __attribute__((address_space(3))) u32 LU32;
__device__ __forceinline__ void glds16(const void* g, void* l) {
  __builtin_amdgcn_global_load_lds((GU32*)g, (LU32*)l, 16, 0, 0);
}

// ---------------- K1: fused conv + softmax(H) ----------------
// grid 512 = (wq 8)*(b 64); block 256 = 4 waves; tile 64k x 128j, Kdim=512.
// LDS x image per 32d-tile: granule(d,h) at g = d*32 + ((h + 2*(d>>3)) & 31),
// 16B granule = x[d][h*32+w0..+3]. Frag read bank spread = 2 lanes/bank (floor).
__global__ __launch_bounds__(256, 2) void k1_conv_softmax(
    const float* __restrict__ x, const float* __restrict__ wgt,
    u16* __restrict__ am)
{
  const int blk = blockIdx.x;
  const int b = blk & 63, wq = blk >> 6;           // XCD = b%8
  const int w0 = wq * 4;
  const int tid = threadIdx.x, lane = tid & 63, wv = tid >> 6;
  const int row = lane & 15, q = lane >> 4;

  __shared__ __align__(16) char smem[33792];       // 2x16KB staging / 64x132 F
  float (*F)[132] = (float (*)[132])smem;

  // staging precompute: 4 granules/thread, inverse of the slot swizzle
  int goff[4];
#pragma unroll
  for (int j2 = 0; j2 < 4; j2++) {
    const int g = j2 * 256 + tid;
    const int d = g >> 5, s = g & 31;
    const int h = (s - 2 * (d >> 3)) & 31;
    goff[j2] = d * 4096 + h * 128;
  }
  const char* xbase = (const char*)x + ((size_t)b << 21) + (size_t)w0 * 4;

  // frag base byte-offsets within a buffer (iteration-invariant)
  int fbase[2];
#pragma unroll
  for (int nt = 0; nt < 2; nt++) {
    const int j = wv * 32 + nt * 16 + row;
    const int h = j >> 2, wl = j & 3;
    fbase[nt] = q * 4096 + ((h + 2 * q) & 31) * 16 + wl * 4;
  }
  const float* wrow = wgt + row * 512 + q * 8;

  f32x4 acc[4][2];
#pragma unroll
  for (int mt = 0; mt < 4; mt++)
#pragma unroll
    for (int nt = 0; nt < 2; nt++) acc[mt][nt] = (f32x4){0.f, 0.f, 0.f, 0.f};

#define STAGE1(d0, buf)                                                        \
  {                                                                            \
    char* lx = smem + (buf) * 16384;                                           \
    _Pragma("unroll")                                                          \
    for (int j2 = 0; j2 < 4; j2++)                                             \
      glds16(xbase + (size_t)(d0) * 4096 + goff[j2],                           \
             lx + (j2 * 256 + tid) * 16);                                      \
  }

  STAGE1(0, 0);
  f32x4 wa[4][2];                                  // w prefetch (f32)
#pragma unroll
  for (int mt = 0; mt < 4; mt++) {
    wa[mt][0] = *(const f32x4*)(wrow + mt * 8192);
    wa[mt][1] = *(const f32x4*)(wrow + mt * 8192 + 4);
  }

  for (int i = 0; i < 16; i++) {
    const int buf = i & 1;
    __syncthreads();                               // drains glds + w prefetch
    short8 af[4];
#pragma unroll
    for (int mt = 0; mt < 4; mt++) {
      S8u t;
      t.q[0] = pk2(wa[mt][0][0], wa[mt][0][1]); t.q[1] = pk2(wa[mt][0][2], wa[mt][0][3]);
      t.q[2] = pk2(wa[mt][1][0], wa[mt][1][1]); t.q[3] = pk2(wa[mt][1][2], wa[mt][1][3]);
      af[mt] = t.s;
    }
    if (i < 15) {
      STAGE1((i + 1) * 32, buf ^ 1);
      const float* wn = wrow + (i + 1) * 32;
#pragma unroll
      for (int mt = 0; mt < 4; mt++) {
        wa[mt][0] = *(const f32x4*)(wn + mt * 8192);
        wa[mt][1] = *(const f32x4*)(wn + mt * 8192 + 4);
      }
    }
    short8 bfv[2];
#pragma unroll
    for (int nt = 0; nt < 2; nt++) {
      const char* p = smem + buf * 16384 + fbase[nt];
      float v0 = *(const float*)(p);
      float v1 = *(const float*)(p + 512);
      float v2 = *(const float*)(p + 1024);
      float v3 = *(const float*)(p + 1536);
      float v4 = *(const float*)(p + 2048);
      float v5 = *(const float*)(p + 2560);
      float v6 = *(const float*)(p + 3072);
      float v7 = *(const float*)(p + 3584);
      S8u t;
      t.q[0] = pk2(v0, v1); t.q[1] = pk2(v2, v3);
      t.q[2] = pk2(v4, v5); t.q[3] = pk2(v6, v7);
      bfv[nt] = t.s;
    }
#pragma unroll
    for (int nt = 0; nt < 2; nt++)
#pragma unroll
      for (int mt = 0; mt < 4; mt++)
        acc[mt][nt] = __builtin_amdgcn_mfma_f32_16x16x32_bf16(af[mt], bfv[nt], acc[mt][nt], 0, 0, 0);
  }
#undef STAGE1

  __syncthreads();                                 // all LDS reads done
#pragma unroll
  for (int mt = 0; mt < 4; mt++)
#pragma unroll
    for (int nt = 0; nt < 2; nt++)
#pragma unroll
      for (int r = 0; r < 4; r++)    // C layout: col=lane&15, row=q*4+r
        F[mt * 16 + q * 4 + r][wv * 32 + nt * 16 + row] = acc[mt][nt][r];
  __syncthreads();

  {  // softmax over h for (k = tid>>2, wl = tid&3); 3 passes, reg-light
    const int k = tid >> 2, wl = tid & 3;
    float m = -1e30f;
#pragma unroll
    for (int h = 0; h < 32; h++) m = fmaxf(m, F[k][h * 4 + wl]);
    float s = 0.f;
#pragma unroll
    for (int h = 0; h < 32; h++) {
      const float e = __expf(F[k][h * 4 + wl] - m);
      F[k][h * 4 + wl] = e;
      s += e;
    }
    const float inv = 1.0f / s;
    u16* ar = am + ((size_t)b << 16) + k * 1024 + w0 + wl;
#pragma unroll
    for (int h = 0; h < 32; h++)
      ar[h * 32] = bf1(F[k][h * 4 + wl] * inv);
  }
}

// ---------------- K2: aggregation + fused normalize ----------------
// grid 512 = (dt 8)*(b 64); block 256 = 4 waves; wave: 64k x 16d; 32 n-iters.
// x LDS image: row r (64), granule s (8): content = x[r][n0 + 4*(s^(r&7)) ..+3];
// frag b128 reads hit the 8-access/bank floor.
__global__ __launch_bounds__(256, 2) void k2_aggregate(
    const float* __restrict__ x, const u16* __restrict__ am,
    const float* __restrict__ cc, float* __restrict__ yw)
{
  const int blk = blockIdx.x;
  const int b = blk & 63, dt = blk >> 6;           // XCD = b%8
  const int tid = threadIdx.x, lane = tid & 63, wv = tid >> 6;
  const int row = lane & 15, q = lane >> 4;

  __shared__ __align__(16) char smem[16384];       // 2 x 8KB

  int aoff[2];                                     // staging: 2 granules/thread
#pragma unroll
  for (int j = 0; j < 2; j++) {
    const int f = j * 256 + tid;
    const int r = f >> 3, s = f & 7;
    aoff[j] = r * 4096 + 4 * (s ^ (r & 7)) * 4;
  }
  const char* xbase = (const char*)x + ((size_t)b << 21) + (size_t)dt * 64 * 4096;
  const u16* ab = am + ((size_t)b << 16) + row * 1024 + q * 8;

  const int rB = wv * 16 + row;
  const int su = (2 * q) ^ (rB & 7);
  const int fo0 = (rB * 8 + su) * 16;              // iteration-invariant
  const int fo1 = (rB * 8 + (su ^ 1)) * 16;

#define STAGE2(n0, buf)                                                        \
  {                                                                            \
    char* lx = smem + (buf) * 8192;                                            \
    _Pragma("unroll")                                                          \
    for (int j = 0; j < 2; j++)                                                \
      glds16(xbase + (size_t)(n0) * 4 + aoff[j],                               \
             lx + (j * 256 + tid) * 16);                                       \
  }

  f32x4 acc[4];
#pragma unroll
  for (int mt = 0; mt < 4; mt++) acc[mt] = (f32x4){0.f, 0.f, 0.f, 0.f};

  STAGE2(0, 0);
  short8 sa[4];                                    // a prefetch (bf16, no pack)
#pragma unroll
  for (int mt = 0; mt < 4; mt++) sa[mt] = *(const short8*)(ab + mt * 16384);

  for (int i = 0; i < 32; i++) {
    const int buf = i & 1;
    __syncthreads();
    short8 af[4];
#pragma unroll
    for (int mt = 0; mt < 4; mt++) af[mt] = sa[mt];
    if (i < 31) {
      STAGE2((i + 1) * 32, buf ^ 1);
      const u16* an = ab + (i + 1) * 32;
#pragma unroll
      for (int mt = 0; mt < 4; mt++) sa[mt] = *(const short8*)(an + mt * 16384);
    }
    f32x4 g0 = *(const f32x4*)(smem + buf * 8192 + fo0);  // cols 8q..8q+3
    f32x4 g1 = *(const f32x4*)(smem + buf * 8192 + fo1);  // cols 8q+4..8q+7
    S8u t;
    t.q[0] = pk2(g0[0], g0[1]); t.q[1] = pk2(g0[2], g0[3]);
    t.q[2] = pk2(g1[0], g1[1]); t.q[3] = pk2(g1[2], g1[3]);
    const short8 bfv = t.s;
#pragma unroll
    for (int mt = 0; mt < 4; mt++)
      acc[mt] = __builtin_amdgcn_mfma_f32_16x16x32_bf16(af[mt], bfv, acc[mt], 0, 0, 0);
  }
#undef STAGE2

  // epilogue: lane holds 16 k's for d = dcol; norm over k wave-local (quads)
  const int dcol = dt * 64 + wv * 16 + row;
  float v[16]; float ss = 0.f;
#pragma unroll
  for (int mt = 0; mt < 4; mt++)
#pragma unroll
    for (int r = 0; r < 4; r++) {
      const int k = mt * 16 + q * 4 + r;
      const float tv = acc[mt][r] - 32.0f * cc[k * 512 + dcol];  // Sum_n a = 32 exact
      v[mt * 4 + r] = tv; ss += tv * tv;
    }
  ss += __shfl_xor(ss, 16);
  ss += __shfl_xor(ss, 32);
  const float rn = 1.0f / fmaxf(sqrtf(ss), 1e-12f);  // 2nd normalize is identity
  float* yb = yw + ((size_t)b << 15) + dcol;
#pragma unroll
  for (int mt = 0; mt < 4; mt++)
#pragma unroll
    for (int r = 0; r < 4; r++)
      yb[(size_t)(mt * 16 + q * 4 + r) << 9] = v[mt * 4 + r] * rn;
}

// ---------------- K3: (B,K,D) -> (D,K,B) ----------------
__global__ __launch_bounds__(256) void k3_transpose(
    const float* __restrict__ yw, float* __restrict__ out)
{
  const int blk = blockIdx.x;
  const int k = blk & 63;
  const int dt = blk >> 6;
  const int d0 = dt * 64;
  const int tid = threadIdx.x;
  __shared__ float T[64][68];
  {
    const int bl = tid >> 2, seg = tid & 3;
    const float* src = yw + (size_t)bl * 32768 + k * 512 + d0 + seg * 16;
#pragma unroll
    for (int i = 0; i < 4; i++) {
      f32x4 v = *(const f32x4*)(src + i * 4);
#pragma unroll
      for (int jj = 0; jj < 4; jj++) T[seg * 16 + i * 4 + jj][bl] = v[jj];
    }
  }
  __syncthreads();
  {
    const int dl = tid >> 2, bseg = tid & 3;
    float* dst = out + (size_t)(d0 + dl) * 4096 + k * 64 + bseg * 16;
    const float* srcT = &T[dl][bseg * 16];
#pragma unroll
    for (int i = 0; i < 4; i++)
      *(f32x4*)(dst + i * 4) = *(const f32x4*)(srcT + i * 4);
  }
}

extern "C" void kernel_launch(void* const* d_in, const int* in_sizes, int n_in,
                              void* d_out, int out_size, void* d_ws, size_t ws_size,
                              hipStream_t stream) {
  const float* x = (const float*)d_in[0];
  const float* w = (const float*)d_in[1];
  const float* c = (const float*)d_in[2];
  float* out = (float*)d_out;
  char* ws = (char*)d_ws;
  u16*   a_ws = (u16*)ws;                                    // 8.4 MiB bf16 a (B,K,N)
  float* yw   = (float*)(ws + (size_t)16 * 1024 * 1024);     // 8.4 MiB f32 (B,K,D)
  k1_conv_softmax<<<dim3(512), dim3(256), 0, stream>>>(x, w, a_ws);
  k2_aggregate   <<<dim3(512), dim3(256), 0, stream>>>(x, a_ws, c, yw);
  k3_transpose   <<<dim3(512), dim3(256), 0, stream>>>(yw, out);
}

// Round 6
// 241.242 us; speedup vs baseline: 1.1623x; 1.1623x over previous
//
#include <hip/hip_runtime.h>

// NetVladCNN: B=64, D=512, H=W=32 (N=1024), K=64
// K0 : pack w f32 -> bf16 padded LDS-image (16 d-blocks)[64 k][80 B] in ws
// K1 : feat = w @ x[b] per (b, 128n-tile). x staged f32 via global_load_lds
//      (double-buffered, 1-KB coalesced bursts); w frags from pre-padded bf16
//      image (conflict-free b128). feat f32 -> ws.
// K1b: softmax over H -> a bf16 (B,K,N). XCD-aligned (blk&63==b) so feat[b]
//      reads hit the same XCD L2 that K1 wrote.
// K2 : V = a @ x^T - 32*c per (b, 64d). x via glds, granule swizzle
//      col=4*(s^(r&7)) -> b128 frag reads at 8-access/bank floor; a frags
//      direct global bf16 prefetched (L2-hot). Fused L2-norm over k -> yw.
// K3 : transpose (B,K,D) -> out (D,K,B)
// XCD: blk&63 = b for K1/K1b/K2 -> all same-b blocks on one XCD's L2.

typedef __attribute__((ext_vector_type(8))) short short8;
typedef __attribute__((ext_vector_type(8))) unsigned short u16x8;
typedef __attribute__((ext_vector_type(4))) float f32x4;
typedef unsigned short u16;
typedef unsigned int u32;

union S8u { u32 q[4]; short8 s; };

__device__ __forceinline__ u32 pk2(float lo, float hi) {  // RNE bf16 pair pack
  union { float f; u32 u; } a, b; a.f = lo; b.f = hi;
  u32 xl = (a.u + 0x7fffu + ((a.u >> 16) & 1u)) >> 16;
  u32 xh = (b.u + 0x7fffu + ((b.u >> 16) & 1u)) & 0xffff0000u;
  return xl | xh;
}

__device__ __forceinline__ u16 bf1(float f) {
  union { float f; u32 u; } a; a.f = f;
  return (u16)((a.u + 0x7fffu + ((a.u >> 16) & 1u)) >> 16);
}

typedef const __attribute__((address_space(1))) u32 GU32;
typedef __attribute__((address_space(3))) u32 LU32;
__device__ __forceinline__ void glds16(const void* g, void* l) {
  __builtin_amdgcn_global_load_lds((GU32*)g, (LU32*)l, 16, 0, 0);
}

// ---------------- K0: pack w into padded bf16 image ----------------
// wsw image: [i=d-block 16][k 64][40 u16] (32 data + 8 pad) = 80 KB
__global__ __launch_bounds__(256) void k0_packw(
    const float* __restrict__ w, u16* __restrict__ wsw)
{
  const int tg = blockIdx.x * 256 + threadIdx.x;   // 8192 threads
  const int dd4 = tg & 7, i = (tg >> 3) & 15, k = tg >> 7;
  f32x4 v = *(const f32x4*)(w + k * 512 + i * 32 + dd4 * 4);
  u32* dst = (u32*)(wsw + ((size_t)i * 64 + k) * 40 + dd4 * 4);
  dst[0] = pk2(v[0], v[1]);
  dst[1] = pk2(v[2], v[3]);
}

// ---------------- K1: features GEMM (glds double-buffer) ----------------
// grid 512 = (ntile 8)*(b 64); block 256 = 4 waves; block tile 64k x 128n, K=512.
__global__ __launch_bounds__(256, 2) void k1_features(
    const float* __restrict__ x, const u16* __restrict__ wsw,
    float* __restrict__ feat)
{
  const int blk = blockIdx.x;
  const int b = blk & 63, nt8 = blk >> 6;          // XCD = b%8
  const int nb = nt8 * 128;
  const int tid = threadIdx.x, lane = tid & 63, wv = tid >> 6;
  const int row = lane & 15, q = lane >> 4;

  __shared__ __align__(16) float xs[2][32][128];   // 32 KB
  __shared__ __align__(16) u16 wls[2][64][40];     // 10 KB

  const char* xbase = (const char*)(x + ((size_t)b << 19) + nb);
  const char* wbase = (const char*)wsw;
  const int dd0 = tid >> 5, cby = (tid & 31) * 16; // x glds decomposition

  f32x4 acc[4][2];
#pragma unroll
  for (int mt = 0; mt < 4; mt++)
#pragma unroll
    for (int nt = 0; nt < 2; nt++) acc[mt][nt] = (f32x4){0.f, 0.f, 0.f, 0.f};

#define STAGE1(d0, buf)                                                        \
  {                                                                            \
    char* lx = (char*)&xs[buf][0][0];                                          \
    _Pragma("unroll")                                                          \
    for (int j = 0; j < 4; j++) {                                              \
      const int dd = j * 8 + dd0;                                              \
      glds16(xbase + (size_t)((d0) + dd) * 4096 + cby,                         \
             lx + j * 4096 + tid * 16);                                        \
    }                                                                          \
    char* lw = (char*)&wls[buf][0][0];                                         \
    const char* gw = wbase + (size_t)((d0) >> 5) * 5120;                       \
    glds16(gw + tid * 16, lw + tid * 16);                                      \
    if (tid < 64) glds16(gw + 4096 + tid * 16, lw + 4096 + tid * 16);          \
  }

  STAGE1(0, 0);
  for (int i = 0; i < 16; i++) {
    const int buf = i & 1;
    __syncthreads();                        // drains glds for buf (vmcnt(0))
    if (i < 15) STAGE1((i + 1) * 32, buf ^ 1);

    short8 af[4];
#pragma unroll
    for (int mt = 0; mt < 4; mt++)
      af[mt] = *(const short8*)&wls[buf][mt * 16 + row][q * 8];
    short8 bfv[2];
#pragma unroll
    for (int nt = 0; nt < 2; nt++) {
      const int n = wv * 32 + nt * 16 + row;
      const int d8 = q * 8;
      float v0 = xs[buf][d8 + 0][n], v1 = xs[buf][d8 + 1][n];
      float v2 = xs[buf][d8 + 2][n], v3 = xs[buf][d8 + 3][n];
      float v4 = xs[buf][d8 + 4][n], v5 = xs[buf][d8 + 5][n];
      float v6 = xs[buf][d8 + 6][n], v7 = xs[buf][d8 + 7][n];
      S8u t;
      t.q[0] = pk2(v0, v1); t.q[1] = pk2(v2, v3);
      t.q[2] = pk2(v4, v5); t.q[3] = pk2(v6, v7);
      bfv[nt] = t.s;
    }
#pragma unroll
    for (int nt = 0; nt < 2; nt++)
#pragma unroll
      for (int mt = 0; mt < 4; mt++)
        acc[mt][nt] = __builtin_amdgcn_mfma_f32_16x16x32_bf16(af[mt], bfv[nt], acc[mt][nt], 0, 0, 0);
  }
#undef STAGE1

  float* fb = feat + ((size_t)b << 16);
  const int nbw = nb + wv * 32;
#pragma unroll
  for (int mt = 0; mt < 4; mt++)
#pragma unroll
    for (int nt = 0; nt < 2; nt++)
#pragma unroll
      for (int r = 0; r < 4; r++)   // C layout: col=lane&15, row=q*4+r
        fb[(mt * 16 + q * 4 + r) * 1024 + nbw + nt * 16 + row] = acc[mt][nt][r];
}

// ---------------- K1b: softmax over H -> a bf16 (B,K,N) ----------------
// grid 1024 = (chunk 16)*(b 64), blk&63 = b -> XCD-aligned with K1/K2.
__global__ __launch_bounds__(256) void k1b_softmax(
    const float* __restrict__ feat, u16* __restrict__ am)
{
  const int blk = blockIdx.x;
  const int b = blk & 63, chunk = blk >> 6;
  const int tid = threadIdx.x, lane = tid & 63, wv = tid >> 6;
  const int rid = b * 64 + chunk * 4 + wv;     // rid = b*64 + k
  const float* f = feat + ((size_t)rid << 10);
  u16* ar = am + ((size_t)rid << 10);
  const int w = lane & 31, half = lane >> 5;
  const int base = w + half * 512;
  float v[16];
  float m = -1e30f;
#pragma unroll
  for (int i = 0; i < 16; i++) { v[i] = f[base + i * 32]; m = fmaxf(m, v[i]); }
  m = fmaxf(m, __shfl_xor(m, 32));
  float s = 0.f;
#pragma unroll
  for (int i = 0; i < 16; i++) { v[i] = __expf(v[i] - m); s += v[i]; }
  s += __shfl_xor(s, 32);
  const float inv = 1.0f / s;
#pragma unroll
  for (int i = 0; i < 16; i++) ar[base + i * 32] = bf1(v[i] * inv);
}

// ---------------- K2: aggregation + fused normalize ----------------
// grid 512 = (dt 8)*(b 64); block 256 = 4 waves; wave: 64k x 16d; 32 n-iters.
// x LDS image: row r (64), granule s (8): content = x[r][n0 + 4*(s^(r&7)) ..+3];
// frag b128 reads hit the 8-access/bank floor.
__global__ __launch_bounds__(256, 2) void k2_aggregate(
    const float* __restrict__ x, const u16* __restrict__ am,
    const float* __restrict__ cc, float* __restrict__ yw)
{
  const int blk = blockIdx.x;
  const int b = blk & 63, dt = blk >> 6;           // XCD = b%8
  const int tid = threadIdx.x, lane = tid & 63, wv = tid >> 6;
  const int row = lane & 15, q = lane >> 4;

  __shared__ __align__(16) char smem[16384];       // 2 x 8KB

  int aoff[2];                                     // staging: 2 granules/thread
#pragma unroll
  for (int j = 0; j < 2; j++) {
    const int f = j * 256 + tid;
    const int r = f >> 3, s = f & 7;
    aoff[j] = r * 4096 + 4 * (s ^ (r & 7)) * 4;
  }
  const char* xbase = (const char*)x + ((size_t)b << 21) + (size_t)dt * 64 * 4096;
  const u16* ab = am + ((size_t)b << 16) + row * 1024 + q * 8;

  const int rB = wv * 16 + row;
  const int su = (2 * q) ^ (rB & 7);
  const int fo0 = (rB * 8 + su) * 16;              // iteration-invariant
  const int fo1 = (rB * 8 + (su ^ 1)) * 16;

#define STAGE2(n0, buf)                                                        \
  {                                                                            \
    char* lx = smem + (buf) * 8192;                                            \
    _Pragma("unroll")                                                          \
    for (int j = 0; j < 2; j++)                                                \
      glds16(xbase + (size_t)(n0) * 4 + aoff[j],                               \
             lx + (j * 256 + tid) * 16);                                       \
  }

  f32x4 acc[4];
#pragma unroll
  for (int mt = 0; mt < 4; mt++) acc[mt] = (f32x4){0.f, 0.f, 0.f, 0.f};

  STAGE2(0, 0);
  short8 sa[4];                                    // a prefetch (bf16, no pack)
#pragma unroll
  for (int mt = 0; mt < 4; mt++) sa[mt] = *(const short8*)(ab + mt * 16384);

  for (int i = 0; i < 32; i++) {
    const int buf = i & 1;
    __syncthreads();
    short8 af[4];
#pragma unroll
    for (int mt = 0; mt < 4; mt++) af[mt] = sa[mt];
    if (i < 31) {
      STAGE2((i + 1) * 32, buf ^ 1);
      const u16* an = ab + (i + 1) * 32;
#pragma unroll
      for (int mt = 0; mt < 4; mt++) sa[mt] = *(const short8*)(an + mt * 16384);
    }
    f32x4 g0 = *(const f32x4*)(smem + buf * 8192 + fo0);  // cols 8q..8q+3
    f32x4 g1 = *(const f32x4*)(smem + buf * 8192 + fo1);  // cols 8q+4..8q+7
    S8u t;
    t.q[0] = pk2(g0[0], g0[1]); t.q[1] = pk2(g0[2], g0[3]);
    t.q[2] = pk2(g1[0], g1[1]); t.q[3] = pk2(g1[2], g1[3]);
    const short8 bfv = t.s;
#pragma unroll
    for (int mt = 0; mt < 4; mt++)
      acc[mt] = __builtin_amdgcn_mfma_f32_16x16x32_bf16(af[mt], bfv, acc[mt], 0, 0, 0);
  }
#undef STAGE2

  // epilogue: lane holds 16 k's for d = dcol; norm over k wave-local (quads)
  const int dcol = dt * 64 + wv * 16 + row;
  float v[16]; float ss = 0.f;
#pragma unroll
  for (int mt = 0; mt < 4; mt++)
#pragma unroll
    for (int r = 0; r < 4; r++) {
      const int k = mt * 16 + q * 4 + r;
      const float tv = acc[mt][r] - 32.0f * cc[k * 512 + dcol];  // Sum_n a = 32 exact
      v[mt * 4 + r] = tv; ss += tv * tv;
    }
  ss += __shfl_xor(ss, 16);
  ss += __shfl_xor(ss, 32);
  const float rn = 1.0f / fmaxf(sqrtf(ss), 1e-12f);  // 2nd normalize is identity
  float* yb = yw + ((size_t)b << 15) + dcol;
#pragma unroll
  for (int mt = 0; mt < 4; mt++)
#pragma unroll
    for (int r = 0; r < 4; r++)
      yb[(size_t)(mt * 16 + q * 4 + r) << 9] = v[mt * 4 + r] * rn;
}

// ---------------- K3: (B,K,D) -> (D,K,B) ----------------
__global__ __launch_bounds__(256) void k3_transpose(
    const float* __restrict__ yw, float* __restrict__ out)
{
  const int blk = blockIdx.x;
  const int k = blk & 63;
  const int dt = blk >> 6;
  const int d0 = dt * 64;
  const int tid = threadIdx.x;
  __shared__ float T[64][68];
  {
    const int bl = tid >> 2, seg = tid & 3;
    const float* src = yw + (size_t)bl * 32768 + k * 512 + d0 + seg * 16;
#pragma unroll
    for (int i = 0; i < 4; i++) {
      f32x4 v = *(const f32x4*)(src + i * 4);
#pragma unroll
      for (int jj = 0; jj < 4; jj++) T[seg * 16 + i * 4 + jj][bl] = v[jj];
    }
  }
  __syncthreads();
  {
    const int dl = tid >> 2, bseg = tid & 3;
    float* dst = out + (size_t)(d0 + dl) * 4096 + k * 64 + bseg * 16;
    const float* srcT = &T[dl][bseg * 16];
#pragma unroll
    for (int i = 0; i < 4; i++)
      *(f32x4*)(dst + i * 4) = *(const f32x4*)(srcT + i * 4);
  }
}

extern "C" void kernel_launch(void* const* d_in, const int* in_sizes, int n_in,
                              void* d_out, int out_size, void* d_ws, size_t ws_size,
                              hipStream_t stream) {
  const float* x = (const float*)d_in[0];
  const float* w = (const float*)d_in[1];
  const float* c = (const float*)d_in[2];
  float* out = (float*)d_out;
  char* ws = (char*)d_ws;
  float* feat = (float*)ws;                                  // 16.8 MiB f32 logits
  u16*   a_ws = (u16*)(ws + (size_t)17 * 1024 * 1024);       //  8.4 MiB bf16 a (B,K,N)
  float* yw   = (float*)(ws + (size_t)26 * 1024 * 1024);     //  8.4 MiB f32 (B,K,D)
  u16*   wsw  = (u16*)(ws + (size_t)35 * 1024 * 1024);       // 80 KiB padded w image
  k0_packw    <<<dim3(32),   dim3(256), 0, stream>>>(w, wsw);
  k1_features <<<dim3(512),  dim3(256), 0, stream>>>(x, wsw, feat);
  k1b_softmax <<<dim3(1024), dim3(256), 0, stream>>>(feat, a_ws);
  k2_aggregate<<<dim3(512),  dim3(256), 0, stream>>>(x, a_ws, c, yw);
  k3_transpose<<<dim3(512),  dim3(256), 0, stream>>>(yw, out);
}

// Round 7
// 237.724 us; speedup vs baseline: 1.1795x; 1.0148x over previous
//
#include <hip/hip_runtime.h>

// NetVladCNN: B=64, D=512, H=W=32 (N=1024), K=64
// K1 : feat = w @ x[b] per (b, 128n-tile). x staged f32 via global_load_lds
//      (double-buffered, 512B coalesced bursts); w A-frags direct global f32,
//      register-prefetched 1 iter ahead. feat -> ws as bf16 (errors are
//      dominated by the exact 32*c term downstream; bf16 logits are free).
// K1b: softmax over H -> a bf16 (B,K,N). XCD-aligned (blk&63==b).
// K2 : V = a @ x^T - 32*c per (b, 64d). x via glds, granule swizzle
//      col=4*(s^(r&7)) -> b128 frag reads at 8-access/bank floor; a frags
//      direct global bf16 prefetched (L2-hot). Fused L2-norm over k -> yw.
// K3 : transpose (B,K,D) -> out (D,K,B)
// XCD: blk&63 = b for K1/K1b/K2 -> all same-b blocks on one XCD's L2.

typedef __attribute__((ext_vector_type(8))) short short8;
typedef __attribute__((ext_vector_type(4))) float f32x4;
typedef unsigned short u16;
typedef unsigned int u32;

union S8u { u32 q[4]; short8 s; };

__device__ __forceinline__ u32 pk2(float lo, float hi) {  // RNE bf16 pair pack
  union { float f; u32 u; } a, b; a.f = lo; b.f = hi;
  u32 xl = (a.u + 0x7fffu + ((a.u >> 16) & 1u)) >> 16;
  u32 xh = (b.u + 0x7fffu + ((b.u >> 16) & 1u)) & 0xffff0000u;
  return xl | xh;
}

__device__ __forceinline__ u16 bf1(float f) {
  union { float f; u32 u; } a; a.f = f;
  return (u16)((a.u + 0x7fffu + ((a.u >> 16) & 1u)) >> 16);
}

__device__ __forceinline__ float b2f(u16 u) {
  union { u32 u; float f; } t; t.u = ((u32)u) << 16; return t.f;
}

typedef const __attribute__((address_space(1))) u32 GU32;
typedef __attribute__((address_space(3))) u32 LU32;
__device__ __forceinline__ void glds16(const void* g, void* l) {
  __builtin_amdgcn_global_load_lds((GU32*)g, (LU32*)l, 16, 0, 0);
}

// ---------------- K1: features GEMM ----------------
// grid 512 = (ntile 8)*(b 64); block 256 = 4 waves; tile 64k x 128n, Kdim=512.
__global__ __launch_bounds__(256, 2) void k1_features(
    const float* __restrict__ x, const float* __restrict__ wgt,
    u16* __restrict__ feat)
{
  const int blk = blockIdx.x;
  const int b = blk & 63, nt8 = blk >> 6;          // XCD = b%8
  const int nb = nt8 * 128;
  const int tid = threadIdx.x, lane = tid & 63, wv = tid >> 6;
  const int row = lane & 15, q = lane >> 4;

  __shared__ __align__(16) float xs[2][32][128];   // 32 KB

  const char* xbase = (const char*)(x + ((size_t)b << 19) + nb);
  const int dd0 = tid >> 5, cby = (tid & 31) * 16; // x glds decomposition
  const float* wrow = wgt + row * 512 + q * 8;     // + mt*16*512 + d0

  f32x4 acc[4][2];
#pragma unroll
  for (int mt = 0; mt < 4; mt++)
#pragma unroll
    for (int nt = 0; nt < 2; nt++) acc[mt][nt] = (f32x4){0.f, 0.f, 0.f, 0.f};

#define STAGE1(d0, buf)                                                        \
  {                                                                            \
    char* lx = (char*)&xs[buf][0][0];                                          \
    _Pragma("unroll")                                                          \
    for (int j = 0; j < 4; j++)                                                \
      glds16(xbase + (size_t)((d0) + j * 8 + dd0) * 4096 + cby,                \
             lx + j * 4096 + tid * 16);                                        \
  }

  STAGE1(0, 0);
  f32x4 wa[4][2];                                  // w prefetch (f32)
#pragma unroll
  for (int mt = 0; mt < 4; mt++) {
    wa[mt][0] = *(const f32x4*)(wrow + mt * 8192);
    wa[mt][1] = *(const f32x4*)(wrow + mt * 8192 + 4);
  }

  for (int i = 0; i < 16; i++) {
    const int buf = i & 1;
    __syncthreads();                               // drains glds + w prefetch
    short8 af[4];
#pragma unroll
    for (int mt = 0; mt < 4; mt++) {
      S8u t;
      t.q[0] = pk2(wa[mt][0][0], wa[mt][0][1]); t.q[1] = pk2(wa[mt][0][2], wa[mt][0][3]);
      t.q[2] = pk2(wa[mt][1][0], wa[mt][1][1]); t.q[3] = pk2(wa[mt][1][2], wa[mt][1][3]);
      af[mt] = t.s;
    }
    if (i < 15) {
      STAGE1((i + 1) * 32, buf ^ 1);
      const float* wn = wrow + (i + 1) * 32;
#pragma unroll
      for (int mt = 0; mt < 4; mt++) {
        wa[mt][0] = *(const f32x4*)(wn + mt * 8192);
        wa[mt][1] = *(const f32x4*)(wn + mt * 8192 + 4);
      }
    }
    short8 bfv[2];
#pragma unroll
    for (int nt = 0; nt < 2; nt++) {
      const int n = wv * 32 + nt * 16 + row;
      const int d8 = q * 8;
      float v0 = xs[buf][d8 + 0][n], v1 = xs[buf][d8 + 1][n];
      float v2 = xs[buf][d8 + 2][n], v3 = xs[buf][d8 + 3][n];
      float v4 = xs[buf][d8 + 4][n], v5 = xs[buf][d8 + 5][n];
      float v6 = xs[buf][d8 + 6][n], v7 = xs[buf][d8 + 7][n];
      S8u t;
      t.q[0] = pk2(v0, v1); t.q[1] = pk2(v2, v3);
      t.q[2] = pk2(v4, v5); t.q[3] = pk2(v6, v7);
      bfv[nt] = t.s;
    }
#pragma unroll
    for (int nt = 0; nt < 2; nt++)
#pragma unroll
      for (int mt = 0; mt < 4; mt++)
        acc[mt][nt] = __builtin_amdgcn_mfma_f32_16x16x32_bf16(af[mt], bfv[nt], acc[mt][nt], 0, 0, 0);
  }
#undef STAGE1

  u16* fb = feat + ((size_t)b << 16);
  const int nbw = nb + wv * 32;
#pragma unroll
  for (int mt = 0; mt < 4; mt++)
#pragma unroll
    for (int nt = 0; nt < 2; nt++)
#pragma unroll
      for (int r = 0; r < 4; r++)   // C layout: col=lane&15, row=q*4+r
        fb[(mt * 16 + q * 4 + r) * 1024 + nbw + nt * 16 + row] = bf1(acc[mt][nt][r]);
}

// ---------------- K1b: softmax over H -> a bf16 (B,K,N) ----------------
// grid 1024 = (chunk 16)*(b 64), blk&63 = b -> XCD-aligned with K1/K2.
__global__ __launch_bounds__(256) void k1b_softmax(
    const u16* __restrict__ feat, u16* __restrict__ am)
{
  const int blk = blockIdx.x;
  const int b = blk & 63, chunk = blk >> 6;
  const int tid = threadIdx.x, lane = tid & 63, wv = tid >> 6;
  const int rid = b * 64 + chunk * 4 + wv;     // rid = b*64 + k
  const u16* f = feat + ((size_t)rid << 10);
  u16* ar = am + ((size_t)rid << 10);
  const int w = lane & 31, half = lane >> 5;
  const int base = w + half * 512;
  float v[16];
  float m = -1e30f;
#pragma unroll
  for (int i = 0; i < 16; i++) { v[i] = b2f(f[base + i * 32]); m = fmaxf(m, v[i]); }
  m = fmaxf(m, __shfl_xor(m, 32));
  float s = 0.f;
#pragma unroll
  for (int i = 0; i < 16; i++) { v[i] = __expf(v[i] - m); s += v[i]; }
  s += __shfl_xor(s, 32);
  const float inv = 1.0f / s;
#pragma unroll
  for (int i = 0; i < 16; i++) ar[base + i * 32] = bf1(v[i] * inv);
}

// ---------------- K2: aggregation + fused normalize ----------------
// grid 512 = (dt 8)*(b 64); block 256 = 4 waves; wave: 64k x 16d; 32 n-iters.
// x LDS image: row r (64), granule s (8): content = x[r][n0 + 4*(s^(r&7)) ..+3];
// frag b128 reads hit the 8-access/bank floor.
__global__ __launch_bounds__(256, 2) void k2_aggregate(
    const float* __restrict__ x, const u16* __restrict__ am,
    const float* __restrict__ cc, float* __restrict__ yw)
{
  const int blk = blockIdx.x;
  const int b = blk & 63, dt = blk >> 6;           // XCD = b%8
  const int tid = threadIdx.x, lane = tid & 63, wv = tid >> 6;
  const int row = lane & 15, q = lane >> 4;

  __shared__ __align__(16) char smem[16384];       // 2 x 8KB

  int aoff[2];                                     // staging: 2 granules/thread
#pragma unroll
  for (int j = 0; j < 2; j++) {
    const int f = j * 256 + tid;
    const int r = f >> 3, s = f & 7;
    aoff[j] = r * 4096 + 4 * (s ^ (r & 7)) * 4;
  }
  const char* xbase = (const char*)x + ((size_t)b << 21) + (size_t)dt * 64 * 4096;
  const u16* ab = am + ((size_t)b << 16) + row * 1024 + q * 8;

  const int rB = wv * 16 + row;
  const int su = (2 * q) ^ (rB & 7);
  const int fo0 = (rB * 8 + su) * 16;              // iteration-invariant
  const int fo1 = (rB * 8 + (su ^ 1)) * 16;

#define STAGE2(n0, buf)                                                        \
  {                                                                            \
    char* lx = smem + (buf) * 8192;                                            \
    _Pragma("unroll")                                                          \
    for (int j = 0; j < 2; j++)                                                \
      glds16(xbase + (size_t)(n0) * 4 + aoff[j],                               \
             lx + (j * 256 + tid) * 16);                                       \
  }

  f32x4 acc[4];
#pragma unroll
  for (int mt = 0; mt < 4; mt++) acc[mt] = (f32x4){0.f, 0.f, 0.f, 0.f};

  STAGE2(0, 0);
  short8 sa[4];                                    // a prefetch (bf16, no pack)
#pragma unroll
  for (int mt = 0; mt < 4; mt++) sa[mt] = *(const short8*)(ab + mt * 16384);

  for (int i = 0; i < 32; i++) {
    const int buf = i & 1;
    __syncthreads();
    short8 af[4];
#pragma unroll
    for (int mt = 0; mt < 4; mt++) af[mt] = sa[mt];
    if (i < 31) {
      STAGE2((i + 1) * 32, buf ^ 1);
      const u16* an = ab + (i + 1) * 32;
#pragma unroll
      for (int mt = 0; mt < 4; mt++) sa[mt] = *(const short8*)(an + mt * 16384);
    }
    f32x4 g0 = *(const f32x4*)(smem + buf * 8192 + fo0);  // cols 8q..8q+3
    f32x4 g1 = *(const f32x4*)(smem + buf * 8192 + fo1);  // cols 8q+4..8q+7
    S8u t;
    t.q[0] = pk2(g0[0], g0[1]); t.q[1] = pk2(g0[2], g0[3]);
    t.q[2] = pk2(g1[0], g1[1]); t.q[3] = pk2(g1[2], g1[3]);
    const short8 bfv = t.s;
#pragma unroll
    for (int mt = 0; mt < 4; mt++)
      acc[mt] = __builtin_amdgcn_mfma_f32_16x16x32_bf16(af[mt], bfv, acc[mt], 0, 0, 0);
  }
#undef STAGE2

  // epilogue: lane holds 16 k's for d = dcol; norm over k wave-local (quads)
  const int dcol = dt * 64 + wv * 16 + row;
  float v[16]; float ss = 0.f;
#pragma unroll
  for (int mt = 0; mt < 4; mt++)
#pragma unroll
    for (int r = 0; r < 4; r++) {
      const int k = mt * 16 + q * 4 + r;
      const float tv = acc[mt][r] - 32.0f * cc[k * 512 + dcol];  // Sum_n a = 32 exact
      v[mt * 4 + r] = tv; ss += tv * tv;
    }
  ss += __shfl_xor(ss, 16);
  ss += __shfl_xor(ss, 32);
  const float rn = 1.0f / fmaxf(sqrtf(ss), 1e-12f);  // 2nd normalize is identity
  float* yb = yw + ((size_t)b << 15) + dcol;
#pragma unroll
  for (int mt = 0; mt < 4; mt++)
#pragma unroll
    for (int r = 0; r < 4; r++)
      yb[(size_t)(mt * 16 + q * 4 + r) << 9] = v[mt * 4 + r] * rn;
}

// ---------------- K3: (B,K,D) -> (D,K,B) ----------------
__global__ __launch_bounds__(256) void k3_transpose(
    const float* __restrict__ yw, float* __restrict__ out)
{
  const int blk = blockIdx.x;
  const int k = blk & 63;
  const int dt = blk >> 6;
  const int d0 = dt * 64;
  const int tid = threadIdx.x;
  __shared__ float T[64][68];
  {
    const int bl = tid >> 2, seg = tid & 3;
    const float* src = yw + (size_t)bl * 32768 + k * 512 + d0 + seg * 16;
#pragma unroll
    for (int i = 0; i < 4; i++) {
      f32x4 v = *(const f32x4*)(src + i * 4);
#pragma unroll
      for (int jj = 0; jj < 4; jj++) T[seg * 16 + i * 4 + jj][bl] = v[jj];
    }
  }
  __syncthreads();
  {
    const int dl = tid >> 2, bseg = tid & 3;
    float* dst = out + (size_t)(d0 + dl) * 4096 + k * 64 + bseg * 16;
    const float* srcT = &T[dl][bseg * 16];
#pragma unroll
    for (int i = 0; i < 4; i++)
      *(f32x4*)(dst + i * 4) = *(const f32x4*)(srcT + i * 4);
  }
}

extern "C" void kernel_launch(void* const* d_in, const int* in_sizes, int n_in,
                              void* d_out, int out_size, void* d_ws, size_t ws_size,
                              hipStream_t stream) {
  const float* x = (const float*)d_in[0];
  const float* w = (const float*)d_in[1];
  const float* c = (const float*)d_in[2];
  float* out = (float*)d_out;
  char* ws = (char*)d_ws;
  u16*   feat = (u16*)ws;                                    // 8.4 MiB bf16 logits
  u16*   a_ws = (u16*)(ws + (size_t)9 * 1024 * 1024);        // 8.4 MiB bf16 a (B,K,N)
  float* yw   = (float*)(ws + (size_t)18 * 1024 * 1024);     // 8.4 MiB f32 (B,K,D)
  k1_features <<<dim3(512),  dim3(256), 0, stream>>>(x, w, feat);
  k1b_softmax <<<dim3(1024), dim3(256), 0, stream>>>(feat, a_ws);
  k2_aggregate<<<dim3(512),  dim3(256), 0, stream>>>(x, a_ws, c, yw);
  k3_transpose<<<dim3(512),  dim3(256), 0, stream>>>(yw, out);
}